// Round 7
// baseline (5374.635 us; speedup 1.0000x reference)
//
#include <hip/hip_runtime.h>

// ---------------------------------------------------------------------------
// v7 = v6 structure (no LDS in ci-loop, no barriers, clamp+mask edges) with:
//  * repacked weights: [co_block][ci][j][9] so each ci's CB j-groups are one
//    contiguous sequential 1152B scalar stream (v6's 36B-per-1152B-stride
//    layout cost ~18 cold SQC lines per ci -> VALUBusy capped at 51%).
//  * back to P=2, CB=32 (tap-optimal: 12 loads / 576 FMA, NCB halves ->
//    FETCH halves). Same codegen as round-2's proven 64-VGPR kernel.
//  * k4 + pixel_conv fused (bitwise-identical math, kills the 25ch x 1024^2
//    round trip and 8 dispatches).
// ---------------------------------------------------------------------------

// ---------------------------------------------------------------------------
// Weight repack: src wt[co][ci][t] -> dst[((co/cb)*cin + ci)*cb + co%cb][t]
// One launch covers all 9 layers (blockIdx.y = layer).
// ---------------------------------------------------------------------------
struct WRepArgs {
  const float* src[9];
  float*       dst[9];
  int cout[9], cin[9], cb[9];
};

__global__ __launch_bounds__(256) void repack_wts_k(WRepArgs a) {
  const int L = blockIdx.y;
  const int cin = a.cin[L], cout = a.cout[L], cb = a.cb[L];
  const int n = cout * cin * 9;
  const float* s = a.src[L];
  float* d = a.dst[L];
  for (int i = blockIdx.x * 256 + threadIdx.x; i < n; i += gridDim.x * 256) {
    int co  = i / (cin * 9);
    int rem = i - co * (cin * 9);
    int ci  = rem / 9;
    int t   = rem - ci * 9;
    d[(((size_t)(co / cb) * cin + ci) * cb + (co % cb)) * 9 + t] = s[i];
  }
}

// ---------------------------------------------------------------------------
// Direct 3x3 SAME conv + ReLU, fp32, row-range aware. Weights REPACKED.
// Block: 256 threads = 64-wide x (4*P)-tall tile; CB outputs in VGPRs.
// Per ci: 3*(P+2) global taps (voffsets computed once; L1/L2-resident) then
// CB j-groups of 9 sequential s_load weights feeding P*9 fmac each.
// ---------------------------------------------------------------------------
template<int CIN, int COUT, int CB, int P, int W>
__global__ __launch_bounds__(256, 2) void conv3x3_relu_k(
    const float* __restrict__ in, const float* __restrict__ wt,  // wt = repacked
    float* __restrict__ out,
    int in_y0, int in_rows, int out_y0, int out_rows)
{
  static_assert(COUT % CB == 0, "CB must divide COUT");
  constexpr int NCB = COUT / CB;
  constexpr int TW  = 64;
  constexpr int TH  = 4 * P;

  const int n   = blockIdx.z / NCB;           // image index
  const int nb  = blockIdx.z % NCB;           // co-block index
  const int co0 = nb * CB;
  const int lx  = threadIdx.x & 63;
  const int yg  = threadIdx.x >> 6;
  const int x0  = blockIdx.x * TW;
  const int x   = x0 + lx;
  const int oy0 = out_y0 + blockIdx.y * TH;   // image row of tile top
  const int yb  = yg * P;

  const int maxoff = in_rows * W * 4 - 4;     // last valid byte offset in chan

  // ---- per-thread tap offsets + masks (constant across ci) ----
  int   voff[P + 2][3];
  float mrow[P + 2];
#pragma unroll
  for (int r = 0; r < P + 2; ++r) {
    int ry = oy0 + yb + r - 1 - in_y0;        // buffer-relative row
    mrow[r] = (ry >= 0 && ry < in_rows) ? 1.f : 0.f;
    int ryc = ry < 0 ? 0 : (ry >= in_rows ? in_rows - 1 : ry);
    int vo  = (ryc * W + x) * 4;
    voff[r][1] = vo;
    voff[r][0] = (vo > 4 ? vo : 4) - 4;       // clamped left tap, never < 0
    int vr = vo + 4;
    voff[r][2] = vr < maxoff ? vr : maxoff;   // clamped right tap, in-bounds
  }
  const float ml = (x == 0)     ? 0.f : 1.f;
  const float mr = (x == W - 1) ? 0.f : 1.f;

  const bool interior =
      (x0 > 0) && (x0 + TW < W) &&
      ((oy0 - 1 - in_y0) >= 0) && ((oy0 + TH - in_y0) < in_rows);

  float acc[CB][P];
#pragma unroll
  for (int j = 0; j < CB; ++j)
#pragma unroll
    for (int p = 0; p < P; ++p) acc[j][p] = 0.f;

  const float* inN   = in + (size_t)n * CIN * in_rows * W;  // uniform -> SGPR
  const size_t chbytes = (size_t)in_rows * W * 4;
  const float* wbase = wt + (size_t)nb * CIN * CB * 9;      // repacked slab

#pragma unroll 1
  for (int ci = 0; ci < CIN; ++ci) {
    const char*  bp  = (const char*)inN + (size_t)ci * chbytes;  // scalar step
    const float* wci = wbase + (size_t)ci * CB * 9;              // sequential

    float va[P + 2][3];
#pragma unroll
    for (int r = 0; r < P + 2; ++r)
#pragma unroll
      for (int c = 0; c < 3; ++c)
        va[r][c] = *(const float*)(bp + voff[r][c]);

    if (!interior) {                          // block-uniform branch
#pragma unroll
      for (int r = 0; r < P + 2; ++r) {
#pragma unroll
        for (int c = 0; c < 3; ++c) {
          float m = mrow[r];
          if (c == 0) m *= ml;
          if (c == 2) m *= mr;
          va[r][c] *= m;
        }
      }
    }

#pragma unroll
    for (int j = 0; j < CB; ++j) {
      const float* wp = wci + j * 9;          // contiguous stream
      float w[9];
#pragma unroll
      for (int t = 0; t < 9; ++t) w[t] = wp[t];
#pragma unroll
      for (int t = 0; t < 9; ++t) {
        const int r = t / 3, c = t - r * 3;
#pragma unroll
        for (int p = 0; p < P; ++p)           // p-interleave: indep chains
          acc[j][p] = fmaf(va[p + r][c], w[t], acc[j][p]);
      }
    }
  }

  // ---- epilogue: ReLU + store ----
  float* outN = out + (size_t)n * COUT * out_rows * W;
#pragma unroll
  for (int p = 0; p < P; ++p) {
    const int orow = (oy0 + yb + p) - out_y0;
    if (orow < out_rows) {
#pragma unroll
      for (int j = 0; j < CB; ++j) {
        float v = acc[j][p] < 0.f ? 0.f : acc[j][p];
        outN[((size_t)(co0 + j) * out_rows + orow) * W + x] = v;
      }
    }
  }
}

// ---------------------------------------------------------------------------
// Fused k4 conv (32->25, repacked weights) + per-pixel 5x5 dynamic conv +
// residual. Bitwise-identical to the unfused pair: conv acc order, ReLU,
// then acc0 = h[y,x]; loop kw,kh: fmaf(h_pad[y+kh-2,x+kw-2], kv, acc0).
// h taps come from a zero-padded LDS halo tile (same values as before).
// in = A strip (32, in_rows, 1024); h, out = full (1024,1024) images.
// Output rows [out_y0, out_y0 + gridDim.y*8).
// ---------------------------------------------------------------------------
template<int CIN, int P>
__global__ __launch_bounds__(256, 2) void conv_k4_pixconv_k(
    const float* __restrict__ in, const float* __restrict__ wt,  // repacked k4
    const float* __restrict__ h, float* __restrict__ out,
    int in_y0, int in_rows, int out_y0)
{
  constexpr int CB = 25;
  constexpr int TW = 64, TH = 4 * P, W = 1024;

  const int lx  = threadIdx.x & 63;
  const int yg  = threadIdx.x >> 6;
  const int x0  = blockIdx.x * TW;
  const int x   = x0 + lx;
  const int oy0 = out_y0 + blockIdx.y * TH;
  const int yb  = yg * P;

  // ---- stage h halo tile (TH+4) x (TW+4), zero-padded ----
  __shared__ float htile[TH + 4][TW + 4];
  for (int t = threadIdx.x; t < (TH + 4) * (TW + 4); t += 256) {
    int r = t / (TW + 4), c = t - r * (TW + 4);
    int yy = oy0 + r - 2, xx = x0 + c - 2;
    float v = 0.f;
    if (yy >= 0 && yy < 1024 && xx >= 0 && xx < W) v = h[(size_t)yy * W + xx];
    htile[r][c] = v;
  }
  __syncthreads();

  const int maxoff = in_rows * W * 4 - 4;

  int   voff[P + 2][3];
  float mrow[P + 2];
#pragma unroll
  for (int r = 0; r < P + 2; ++r) {
    int ry = oy0 + yb + r - 1 - in_y0;
    mrow[r] = (ry >= 0 && ry < in_rows) ? 1.f : 0.f;
    int ryc = ry < 0 ? 0 : (ry >= in_rows ? in_rows - 1 : ry);
    int vo  = (ryc * W + x) * 4;
    voff[r][1] = vo;
    voff[r][0] = (vo > 4 ? vo : 4) - 4;
    int vr = vo + 4;
    voff[r][2] = vr < maxoff ? vr : maxoff;
  }
  const float ml = (x == 0)     ? 0.f : 1.f;
  const float mr = (x == W - 1) ? 0.f : 1.f;

  const bool interior =
      (x0 > 0) && (x0 + TW < W) &&
      ((oy0 - 1 - in_y0) >= 0) && ((oy0 + TH - in_y0) < in_rows);

  float acc[CB][P];
#pragma unroll
  for (int j = 0; j < CB; ++j)
#pragma unroll
    for (int p = 0; p < P; ++p) acc[j][p] = 0.f;

  const size_t chbytes = (size_t)in_rows * W * 4;

#pragma unroll 1
  for (int ci = 0; ci < CIN; ++ci) {
    const char*  bp  = (const char*)in + (size_t)ci * chbytes;
    const float* wci = wt + (size_t)ci * CB * 9;

    float va[P + 2][3];
#pragma unroll
    for (int r = 0; r < P + 2; ++r)
#pragma unroll
      for (int c = 0; c < 3; ++c)
        va[r][c] = *(const float*)(bp + voff[r][c]);

    if (!interior) {
#pragma unroll
      for (int r = 0; r < P + 2; ++r) {
#pragma unroll
        for (int c = 0; c < 3; ++c) {
          float m = mrow[r];
          if (c == 0) m *= ml;
          if (c == 2) m *= mr;
          va[r][c] *= m;
        }
      }
    }

#pragma unroll
    for (int j = 0; j < CB; ++j) {
      const float* wp = wci + j * 9;
      float w[9];
#pragma unroll
      for (int t = 0; t < 9; ++t) w[t] = wp[t];
#pragma unroll
      for (int t = 0; t < 9; ++t) {
        const int r = t / 3, c = t - r * 3;
#pragma unroll
        for (int p = 0; p < P; ++p)
          acc[j][p] = fmaf(va[p + r][c], w[t], acc[j][p]);
      }
    }
  }

  // ---- epilogue: ReLU kernels in-register, 5x5 dynamic conv + residual ----
#pragma unroll
  for (int p = 0; p < P; ++p) {
    float a = htile[yb + p + 2][lx + 2];       // residual h
#pragma unroll
    for (int kw = 0; kw < 5; ++kw) {
#pragma unroll
      for (int kh = 0; kh < 5; ++kh) {
        float kv = acc[kw * 5 + kh][p];
        kv = kv < 0.f ? 0.f : kv;
        a = fmaf(htile[yb + p + kh][lx + kw], kv, a);
      }
    }
    out[(size_t)(oy0 + yb + p) * W + x] = a;
  }
}

// ---------------------------------------------------------------------------
// PixelShuffle r=4 + ReLU, BOTH images: (2,16,256,256) -> (2,1024,1024)
// ---------------------------------------------------------------------------
__global__ __launch_bounds__(256) void pixel_shuffle_relu_k(
    const float* __restrict__ in, float* __restrict__ out)
{
  int i = blockIdx.x * 256 + threadIdx.x;      // over 2*1024*1024
  int n = i >> 20;
  int p = i & 1048575;
  int x = p & 1023, y = p >> 10;
  int c = (y & 3) * 4 + (x & 3);
  float v = in[((size_t)(n * 16 + c) * 256 + (y >> 2)) * 256 + (x >> 2)];
  out[i] = v < 0.f ? 0.f : v;
}

// ---------------------------------------------------------------------------
// Launch. Workspace: Hs (8 MiB) | WREP (512 KiB) | A | B  (A/B as before).
// ---------------------------------------------------------------------------
extern "C" void kernel_launch(void* const* d_in, const int* in_sizes, int n_in,
                              void* d_out, int out_size, void* d_ws, size_t ws_size,
                              hipStream_t stream) {
  const float* x    = (const float*)d_in[0];
  const float* w[9] = { (const float*)d_in[1], (const float*)d_in[2],
                        (const float*)d_in[3], (const float*)d_in[4],
                        (const float*)d_in[5], (const float*)d_in[6],
                        (const float*)d_in[7], (const float*)d_in[8],
                        (const float*)d_in[9] };
  // layer order: e1 e2 e3 d1 d2 k1 k2 k3 k4
  const int LCO[9] = {16, 32, 64, 32, 16, 32, 64, 32, 25};
  const int LCI[9] = { 1, 16, 32, 64, 32,  1, 32, 64, 32};
  const int LCB[9] = {16, 32, 32, 32, 16, 32, 32, 32, 25};

  const size_t HS_SZ   = 8388608;               // 2 * 1024*1024 * 4
  const size_t WREP_SZ = 524288;                // repacked weights (<=435 KB)
  const size_t AMIN    = 16777216;              // 2 img * 32ch @256²
  const size_t BMIN    = 33554432;              // 2 img * 64ch @256²

  int S = 64;
  {
    const int cand[5] = {1024, 512, 256, 128, 64};
    for (int i = 0; i < 5; ++i) {
      int s = cand[i];
      size_t a = 32ull * (size_t)(s + 6) * 1024 * 4; if (a < AMIN) a = AMIN;
      size_t b = 64ull * (size_t)(s + 4) * 1024 * 4; if (b < BMIN) b = BMIN;
      if (HS_SZ + WREP_SZ + a + b <= ws_size) { S = s; break; }
    }
  }
  size_t A_SZ = 32ull * (size_t)(S + 6) * 1024 * 4; if (A_SZ < AMIN) A_SZ = AMIN;

  char* ws = (char*)d_ws;
  float* Hs   = (float*)(ws);
  float* WREP = (float*)(ws + HS_SZ);
  float* A    = (float*)(ws + HS_SZ + WREP_SZ);
  float* B    = (float*)(ws + HS_SZ + WREP_SZ + A_SZ);
  float* outp = (float*)d_out;

  // ---- repack all weights (one dispatch) ----
  WRepArgs ra;
  float* wr[9];
  {
    size_t off = 0;
    for (int L = 0; L < 9; ++L) {
      wr[L] = WREP + off;
      ra.src[L] = w[L]; ra.dst[L] = wr[L];
      ra.cout[L] = LCO[L]; ra.cin[L] = LCI[L]; ra.cb[L] = LCB[L];
      off += (size_t)LCO[L] * LCI[L] * 9;
    }
  }
  dim3 blk(256);
  repack_wts_k<<<dim3(8, 9), blk, 0, stream>>>(ra);

  // ---- encoder/decoder @256², both images per dispatch, ping-pong A<->B ----
  // P=2 -> TH=8. grid: (256/64, 256/8, 2*NCB)
  conv3x3_relu_k<1, 16, 16, 2, 256><<<dim3(4, 32, 2), blk, 0, stream>>>(x, wr[0], B, 0, 256, 0, 256);
  conv3x3_relu_k<16, 32, 32, 2, 256><<<dim3(4, 32, 2), blk, 0, stream>>>(B, wr[1], A, 0, 256, 0, 256);
  conv3x3_relu_k<32, 64, 32, 2, 256><<<dim3(4, 32, 4), blk, 0, stream>>>(A, wr[2], B, 0, 256, 0, 256);
  conv3x3_relu_k<64, 32, 32, 2, 256><<<dim3(4, 32, 2), blk, 0, stream>>>(B, wr[3], A, 0, 256, 0, 256);
  conv3x3_relu_k<32, 16, 16, 2, 256><<<dim3(4, 32, 2), blk, 0, stream>>>(A, wr[4], B, 0, 256, 0, 256);
  pixel_shuffle_relu_k<<<dim3(8192), blk, 0, stream>>>(B, Hs);

  // ---- kernel-prediction branch + fused dynamic conv, per image, strips ----
  const int nstr = 1024 / S;
  for (int n = 0; n < 2; ++n) {
    const float* himg = Hs + (size_t)n * 1048576;
    float* outn = outp + (size_t)n * 1048576;
    for (int s = 0; s < nstr; ++s) {
      const int r0 = s * S, r1 = r0 + S;
      const int z1y0 = (r0 - 3 > 0) ? r0 - 3 : 0;
      const int z1r  = ((r1 + 3 < 1024) ? r1 + 3 : 1024) - z1y0;
      const int z2y0 = (r0 - 2 > 0) ? r0 - 2 : 0;
      const int z2r  = ((r1 + 2 < 1024) ? r1 + 2 : 1024) - z2y0;
      const int z3y0 = (r0 - 1 > 0) ? r0 - 1 : 0;
      const int z3r  = ((r1 + 1 < 1024) ? r1 + 1 : 1024) - z3y0;
      const int g1 = (z1r + 7) / 8, g2 = (z2r + 7) / 8, g3 = (z3r + 7) / 8;

      conv3x3_relu_k<1, 32, 32, 2, 1024><<<dim3(16, g1, 1), blk, 0, stream>>>(
          himg, wr[5], A, 0, 1024, z1y0, z1r);
      conv3x3_relu_k<32, 64, 32, 2, 1024><<<dim3(16, g2, 2), blk, 0, stream>>>(
          A, wr[6], B, z1y0, z1r, z2y0, z2r);
      conv3x3_relu_k<64, 32, 32, 2, 1024><<<dim3(16, g3, 1), blk, 0, stream>>>(
          B, wr[7], A, z2y0, z2r, z3y0, z3r);
      conv_k4_pixconv_k<32, 2><<<dim3(16, S / 8, 1), blk, 0, stream>>>(
          A, wr[8], himg, outn, z3y0, z3r, r0);
    }
  }
}

// Round 8
// 2997.817 us; speedup vs baseline: 1.7928x; 1.7928x over previous
//
#include <hip/hip_runtime.h>

// ---------------------------------------------------------------------------
// v8 = v6 conv kernel VERBATIM (direct d_in weights — round-7's repack
// regressed 1.56x: old [co][ci][9] layout is already ci-sequential per j,
// and the repacked indexing shrank the compiler's s_load look-ahead,
// SGPR 80->64, VALUBusy 51->23%)
// + fused k4+pixel_conv (direct weights, bitwise-identical math): kills the
// 25ch x 1024^2 k4 round-trip and the pixel_conv dispatches.
// ---------------------------------------------------------------------------

// ---------------------------------------------------------------------------
// Direct 3x3 SAME conv + ReLU, fp32, row-range aware (= v6, proven 285us
// on the 1024^2 CIN=32->64 layer; VALUBusy 51%, no spill).
//
// Block: 256 threads = 64-wide x (4*P)-tall output tile. Thread (lx, yg)
// owns P output rows at column x. CB output channels accumulate in VGPRs.
// P=4: 72cy FMA per 36B wave-uniform scalar weight fetch -> latency mostly
// hidden (P=2 measured 37% VALUBusy, P=4 measured 51%).
// __launch_bounds__(256,2): VGPR cap 256 -> spills impossible (round-3's
// cliff); actual use ~76 keeps 4+ waves/SIMD.
// ---------------------------------------------------------------------------
template<int CIN, int COUT, int CB, int P, int W>
__global__ __launch_bounds__(256, 2) void conv3x3_relu_k(
    const float* __restrict__ in, const float* __restrict__ wt,
    float* __restrict__ out,
    int in_y0, int in_rows, int out_y0, int out_rows)
{
  static_assert(COUT % CB == 0, "CB must divide COUT");
  constexpr int NCB = COUT / CB;
  constexpr int TW  = 64;
  constexpr int TH  = 4 * P;

  const int n   = blockIdx.z / NCB;           // image index
  const int co0 = (blockIdx.z % NCB) * CB;
  const int lx  = threadIdx.x & 63;
  const int yg  = threadIdx.x >> 6;
  const int x0  = blockIdx.x * TW;
  const int x   = x0 + lx;
  const int oy0 = out_y0 + blockIdx.y * TH;   // image row of tile top
  const int yb  = yg * P;

  const int maxoff = in_rows * W * 4 - 4;     // last valid byte offset in chan

  // ---- per-thread tap offsets + masks (constant across ci) ----
  int   voff[P + 2][3];
  float mrow[P + 2];
#pragma unroll
  for (int r = 0; r < P + 2; ++r) {
    int ry = oy0 + yb + r - 1 - in_y0;        // buffer-relative row
    mrow[r] = (ry >= 0 && ry < in_rows) ? 1.f : 0.f;
    int ryc = ry < 0 ? 0 : (ry >= in_rows ? in_rows - 1 : ry);
    int vo  = (ryc * W + x) * 4;
    voff[r][1] = vo;
    voff[r][0] = (vo > 4 ? vo : 4) - 4;       // clamped left tap, never < 0
    int vr = vo + 4;
    voff[r][2] = vr < maxoff ? vr : maxoff;   // clamped right tap, in-bounds
  }
  const float ml = (x == 0)     ? 0.f : 1.f;
  const float mr = (x == W - 1) ? 0.f : 1.f;

  const bool interior =
      (x0 > 0) && (x0 + TW < W) &&
      ((oy0 - 1 - in_y0) >= 0) && ((oy0 + TH - in_y0) < in_rows);

  float acc[CB][P];
#pragma unroll
  for (int j = 0; j < CB; ++j)
#pragma unroll
    for (int p = 0; p < P; ++p) acc[j][p] = 0.f;

  const float* inN = in + (size_t)n * CIN * in_rows * W;   // uniform -> SGPR
  const size_t chbytes = (size_t)in_rows * W * 4;

#pragma unroll 1
  for (int ci = 0; ci < CIN; ++ci) {
    const char* bp = (const char*)inN + (size_t)ci * chbytes;  // scalar step

    float va[P + 2][3];
#pragma unroll
    for (int r = 0; r < P + 2; ++r)
#pragma unroll
      for (int c = 0; c < 3; ++c)
        va[r][c] = *(const float*)(bp + voff[r][c]);

    if (!interior) {                          // block-uniform branch
#pragma unroll
      for (int r = 0; r < P + 2; ++r) {
#pragma unroll
        for (int c = 0; c < 3; ++c) {
          float m = mrow[r];
          if (c == 0) m *= ml;
          if (c == 2) m *= mr;
          va[r][c] *= m;
        }
      }
    }

#pragma unroll
    for (int j = 0; j < CB; ++j) {
      const float* wp = wt + ((size_t)(co0 + j) * CIN + ci) * 9;  // uniform
      float w[9];
#pragma unroll
      for (int t = 0; t < 9; ++t) w[t] = wp[t];
#pragma unroll
      for (int t = 0; t < 9; ++t) {
        const int r = t / 3, c = t - r * 3;
#pragma unroll
        for (int p = 0; p < P; ++p)           // p-interleave: indep chains
          acc[j][p] = fmaf(va[p + r][c], w[t], acc[j][p]);
      }
    }
  }

  // ---- epilogue: ReLU + store ----
  float* outN = out + (size_t)n * COUT * out_rows * W;
#pragma unroll
  for (int p = 0; p < P; ++p) {
    const int orow = (oy0 + yb + p) - out_y0;
    if (orow < out_rows) {
#pragma unroll
      for (int j = 0; j < CB; ++j) {
        float v = acc[j][p] < 0.f ? 0.f : acc[j][p];
        outN[((size_t)(co0 + j) * out_rows + orow) * W + x] = v;
      }
    }
  }
}

// ---------------------------------------------------------------------------
// Fused k4 conv (32->25, DIRECT weights, v6's proven CB=25/P=2 config) +
// per-pixel 5x5 dynamic conv + residual. Bitwise-identical to the unfused
// pair: conv acc order, ReLU, then a = h[y,x]; loop kw,kh:
// a = fmaf(h_pad[y+kh-2,x+kw-2], relu(acc[kw*5+kh]), a).
// h taps from a zero-padded LDS halo tile (same values as the old kernel).
// in = A strip (32, in_rows, 1024); h, out = full (1024,1024) images.
// ---------------------------------------------------------------------------
template<int CIN, int P>
__global__ __launch_bounds__(256, 2) void conv_k4_pixconv_k(
    const float* __restrict__ in, const float* __restrict__ wt,
    const float* __restrict__ h, float* __restrict__ out,
    int in_y0, int in_rows, int out_y0)
{
  constexpr int CB = 25;
  constexpr int TW = 64, TH = 4 * P, W = 1024;

  const int lx  = threadIdx.x & 63;
  const int yg  = threadIdx.x >> 6;
  const int x0  = blockIdx.x * TW;
  const int x   = x0 + lx;
  const int oy0 = out_y0 + blockIdx.y * TH;
  const int yb  = yg * P;

  // ---- stage h halo tile (TH+4) x (TW+4), zero-padded ----
  __shared__ float htile[TH + 4][TW + 4];
  for (int t = threadIdx.x; t < (TH + 4) * (TW + 4); t += 256) {
    int r = t / (TW + 4), c = t - r * (TW + 4);
    int yy = oy0 + r - 2, xx = x0 + c - 2;
    float v = 0.f;
    if (yy >= 0 && yy < 1024 && xx >= 0 && xx < W) v = h[(size_t)yy * W + xx];
    htile[r][c] = v;
  }
  __syncthreads();

  const int maxoff = in_rows * W * 4 - 4;

  int   voff[P + 2][3];
  float mrow[P + 2];
#pragma unroll
  for (int r = 0; r < P + 2; ++r) {
    int ry = oy0 + yb + r - 1 - in_y0;
    mrow[r] = (ry >= 0 && ry < in_rows) ? 1.f : 0.f;
    int ryc = ry < 0 ? 0 : (ry >= in_rows ? in_rows - 1 : ry);
    int vo  = (ryc * W + x) * 4;
    voff[r][1] = vo;
    voff[r][0] = (vo > 4 ? vo : 4) - 4;
    int vr = vo + 4;
    voff[r][2] = vr < maxoff ? vr : maxoff;
  }
  const float ml = (x == 0)     ? 0.f : 1.f;
  const float mr = (x == W - 1) ? 0.f : 1.f;

  const bool interior =
      (x0 > 0) && (x0 + TW < W) &&
      ((oy0 - 1 - in_y0) >= 0) && ((oy0 + TH - in_y0) < in_rows);

  float acc[CB][P];
#pragma unroll
  for (int j = 0; j < CB; ++j)
#pragma unroll
    for (int p = 0; p < P; ++p) acc[j][p] = 0.f;

  const size_t chbytes = (size_t)in_rows * W * 4;

#pragma unroll 1
  for (int ci = 0; ci < CIN; ++ci) {
    const char* bp = (const char*)in + (size_t)ci * chbytes;

    float va[P + 2][3];
#pragma unroll
    for (int r = 0; r < P + 2; ++r)
#pragma unroll
      for (int c = 0; c < 3; ++c)
        va[r][c] = *(const float*)(bp + voff[r][c]);

    if (!interior) {
#pragma unroll
      for (int r = 0; r < P + 2; ++r) {
#pragma unroll
        for (int c = 0; c < 3; ++c) {
          float m = mrow[r];
          if (c == 0) m *= ml;
          if (c == 2) m *= mr;
          va[r][c] *= m;
        }
      }
    }

#pragma unroll
    for (int j = 0; j < CB; ++j) {
      const float* wp = wt + ((size_t)j * CIN + ci) * 9;   // direct layout
      float w[9];
#pragma unroll
      for (int t = 0; t < 9; ++t) w[t] = wp[t];
#pragma unroll
      for (int t = 0; t < 9; ++t) {
        const int r = t / 3, c = t - r * 3;
#pragma unroll
        for (int p = 0; p < P; ++p)
          acc[j][p] = fmaf(va[p + r][c], w[t], acc[j][p]);
      }
    }
  }

  // ---- epilogue: ReLU kernels in-register, 5x5 dynamic conv + residual ----
#pragma unroll
  for (int p = 0; p < P; ++p) {
    float a = htile[yb + p + 2][lx + 2];       // residual h
#pragma unroll
    for (int kw = 0; kw < 5; ++kw) {
#pragma unroll
      for (int kh = 0; kh < 5; ++kh) {
        float kv = acc[kw * 5 + kh][p];
        kv = kv < 0.f ? 0.f : kv;
        a = fmaf(htile[yb + p + kh][lx + kw], kv, a);
      }
    }
    out[(size_t)(oy0 + yb + p) * W + x] = a;
  }
}

// ---------------------------------------------------------------------------
// PixelShuffle r=4 + ReLU, BOTH images: (2,16,256,256) -> (2,1024,1024)
// out[n, 4*hh+ii, 4*ww+jj] = in[n, ii*4+jj, hh, ww]
// ---------------------------------------------------------------------------
__global__ __launch_bounds__(256) void pixel_shuffle_relu_k(
    const float* __restrict__ in, float* __restrict__ out)
{
  int i = blockIdx.x * 256 + threadIdx.x;      // over 2*1024*1024
  int n = i >> 20;
  int p = i & 1048575;
  int x = p & 1023, y = p >> 10;
  int c = (y & 3) * 4 + (x & 3);
  float v = in[((size_t)(n * 16 + c) * 256 + (y >> 2)) * 256 + (x >> 2)];
  out[i] = v < 0.f ? 0.f : v;
}

// ---------------------------------------------------------------------------
// Launch. Workspace (adaptive to ws_size):
//   Hs: 8 MiB  — shuffled h, both images, persists
//   A : max(32ch*(S+6)*1024*4, 16.8 MB)  — z1/z3 strip buf; encoder ping (2 img)
//   B : max(64ch*(S+4)*1024*4, 33.6 MB)  — z2 strip buf; encoder pong (2 img)
// S = largest of {1024,512,256,128,64} fitting ws_size.
// Encoder/decoder batches BOTH images per dispatch.
// z-branch runs per image in row strips with halo-recompute; k4+pixel_conv
// fused (identical numerics).
// ---------------------------------------------------------------------------
extern "C" void kernel_launch(void* const* d_in, const int* in_sizes, int n_in,
                              void* d_out, int out_size, void* d_ws, size_t ws_size,
                              hipStream_t stream) {
  const float* x    = (const float*)d_in[0];
  const float* w_e1 = (const float*)d_in[1];
  const float* w_e2 = (const float*)d_in[2];
  const float* w_e3 = (const float*)d_in[3];
  const float* w_d1 = (const float*)d_in[4];
  const float* w_d2 = (const float*)d_in[5];
  const float* w_k1 = (const float*)d_in[6];
  const float* w_k2 = (const float*)d_in[7];
  const float* w_k3 = (const float*)d_in[8];
  const float* w_k4 = (const float*)d_in[9];

  const size_t HS_SZ = 8388608;                 // 2 * 1024*1024 * 4
  const size_t AMIN  = 16777216;                // 2 img * 32ch @256²
  const size_t BMIN  = 33554432;                // 2 img * 64ch @256²

  int S = 64;
  {
    const int cand[5] = {1024, 512, 256, 128, 64};
    for (int i = 0; i < 5; ++i) {
      int s = cand[i];
      size_t a = 32ull * (size_t)(s + 6) * 1024 * 4; if (a < AMIN) a = AMIN;
      size_t b = 64ull * (size_t)(s + 4) * 1024 * 4; if (b < BMIN) b = BMIN;
      if (HS_SZ + a + b <= ws_size) { S = s; break; }
    }
  }
  size_t A_SZ = 32ull * (size_t)(S + 6) * 1024 * 4; if (A_SZ < AMIN) A_SZ = AMIN;

  char* ws = (char*)d_ws;
  float* Hs = (float*)(ws);
  float* A  = (float*)(ws + HS_SZ);
  float* B  = (float*)(ws + HS_SZ + A_SZ);
  float* outp = (float*)d_out;

  dim3 blk(256);

  // ---- encoder/decoder @256², both images per dispatch, ping-pong A<->B ----
  // P=4 -> TH=16. grid: (256/64, 256/16, 2*NCB)
  conv3x3_relu_k<1, 16, 16, 4, 256><<<dim3(4, 16, 2), blk, 0, stream>>>(x, w_e1, B, 0, 256, 0, 256);
  conv3x3_relu_k<16, 32, 16, 4, 256><<<dim3(4, 16, 4), blk, 0, stream>>>(B, w_e2, A, 0, 256, 0, 256);
  conv3x3_relu_k<32, 64, 16, 4, 256><<<dim3(4, 16, 8), blk, 0, stream>>>(A, w_e3, B, 0, 256, 0, 256);
  conv3x3_relu_k<64, 32, 16, 4, 256><<<dim3(4, 16, 4), blk, 0, stream>>>(B, w_d1, A, 0, 256, 0, 256);
  conv3x3_relu_k<32, 16, 16, 4, 256><<<dim3(4, 16, 2), blk, 0, stream>>>(A, w_d2, B, 0, 256, 0, 256);
  pixel_shuffle_relu_k<<<dim3(8192), blk, 0, stream>>>(B, Hs);

  // ---- kernel-prediction branch + fused dynamic conv, per image, strips ----
  const int nstr = 1024 / S;
  for (int n = 0; n < 2; ++n) {
    const float* himg = Hs + (size_t)n * 1048576;
    float* outn = outp + (size_t)n * 1048576;
    for (int s = 0; s < nstr; ++s) {
      const int r0 = s * S, r1 = r0 + S;
      const int z1y0 = (r0 - 3 > 0) ? r0 - 3 : 0;
      const int z1r  = ((r1 + 3 < 1024) ? r1 + 3 : 1024) - z1y0;
      const int z2y0 = (r0 - 2 > 0) ? r0 - 2 : 0;
      const int z2r  = ((r1 + 2 < 1024) ? r1 + 2 : 1024) - z2y0;
      const int z3y0 = (r0 - 1 > 0) ? r0 - 1 : 0;
      const int z3r  = ((r1 + 1 < 1024) ? r1 + 1 : 1024) - z3y0;
      const int g1 = (z1r + 15) / 16, g2 = (z2r + 15) / 16, g3 = (z3r + 15) / 16;

      conv3x3_relu_k<1, 32, 16, 4, 1024><<<dim3(16, g1, 2), blk, 0, stream>>>(
          himg, w_k1, A, 0, 1024, z1y0, z1r);
      conv3x3_relu_k<32, 64, 16, 4, 1024><<<dim3(16, g2, 4), blk, 0, stream>>>(
          A, w_k2, B, z1y0, z1r, z2y0, z2r);
      conv3x3_relu_k<64, 32, 16, 4, 1024><<<dim3(16, g3, 2), blk, 0, stream>>>(
          B, w_k3, A, z2y0, z2r, z3y0, z3r);
      conv_k4_pixconv_k<32, 2><<<dim3(16, S / 8, 1), blk, 0, stream>>>(
          A, w_k4, himg, outn, z3y0, z3r, r0);
    }
  }
}